// Round 1
// baseline (382.605 us; speedup 1.0000x reference)
//
#include <hip/hip_runtime.h>
#include <hip/hip_bf16.h>
#include <math.h>

#define D        64      // feature dim
#define NQ       128     // 32*4 queries
#define TS       64      // action rows per tile
#define ASTRIDE  72      // bf16 elems per LDS row: 144 B, 16B-aligned, <=2-way bank alias (free)
#define MARGIN   0.025f  // > 2*(bf16 RNE cosine error bound ~0.008)
#define CAP      128     // max flagged tiles per query
#define CHUNK    21      // contiguous tiles per block: 745 blocks, all resident at 3/CU

typedef __attribute__((ext_vector_type(8))) short  short8;
typedef __attribute__((ext_vector_type(4))) short  short4v;
typedef __attribute__((ext_vector_type(4))) float  f32x4;

__device__ inline unsigned ordf(float f) {
    unsigned u = __float_as_uint(f);
    return (u & 0x80000000u) ? ~u : (u | 0x80000000u);
}

__device__ inline short bf16bits(float f) {
    __hip_bfloat16 h = __float2bfloat16(f);
    return *(short*)&h;
}

__device__ inline float sq4(f32x4 a) {
    float s = 0.f;
    s = fmaf(a.x, a.x, s); s = fmaf(a.y, a.y, s);
    s = fmaf(a.z, a.z, s); s = fmaf(a.w, a.w, s);
    return s;
}

__device__ inline float sq16(f32x4 a, f32x4 b, f32x4 c, f32x4 d) {
    return sq4(a) + sq4(b) + sq4(c) + sq4(d);
}

__device__ inline short8 cvt8(f32x4 a, f32x4 b, float s) {
    short8 r;
    r[0] = bf16bits(a.x * s); r[1] = bf16bits(a.y * s);
    r[2] = bf16bits(a.z * s); r[3] = bf16bits(a.w * s);
    r[4] = bf16bits(b.x * s); r[5] = bf16bits(b.y * s);
    r[6] = bf16bits(b.z * s); r[7] = bf16bits(b.w * s);
    return r;
}

__device__ inline short4v cvt4(f32x4 a, float s) {
    short4v r;
    r[0] = bf16bits(a.x * s); r[1] = bf16bits(a.y * s);
    r[2] = bf16bits(a.z * s); r[3] = bf16bits(a.w * s);
    return r;
}

// K1: block-per-CHUNK of contiguous tiles, double-buffered bf16 LDS tile.
// Per-(q,tile) maxes accumulate in LDS (tbuf) and flush coalesced at block end
// -- removes the 16-lane x 4B x 62.5KB-stride scatter (one dirty line per 4B
// write, write-allocate fetch + cross-XCD ping-pong) of the previous version.
__global__ __launch_bounds__(256, 3)
void k1_score(const float* __restrict__ pred,
              const float* __restrict__ acts,
              float* __restrict__ tmax,
              int ntiles)
{
    __shared__ unsigned short As[2][TS * ASTRIDE];   // normalized bf16 tiles
    __shared__ float tbuf[NQ * CHUNK];               // per-(q,tile) maxes, 10.5 KB

    const int tid  = threadIdx.x;
    const int lane = tid & 63;
    const int wv   = tid >> 6;      // 0..3
    const int quad = lane >> 4;     // 0..3
    const int l15  = lane & 15;

    const int tile0 = blockIdx.x * CHUNK;
    if (tile0 >= ntiles) return;
    const int cn = min(CHUNK, ntiles - tile0);

    // ---- B frags: wave's 32 queries, normalized, bf16. q=(wv*2+nt)*16+l15 ----
    short8 bf[2][2];
#pragma unroll
    for (int nt = 0; nt < 2; ++nt) {
        const int q = (wv * 2 + nt) * 16 + l15;
        const float* P = pred + q * D + quad * 8;
        f32x4 v0 = *(const f32x4*)(P);
        f32x4 v1 = *(const f32x4*)(P + 4);
        f32x4 v2 = *(const f32x4*)(P + 32);
        f32x4 v3 = *(const f32x4*)(P + 36);
        float nb2 = sq16(v0, v1, v2, v3);
        nb2 += __shfl_xor(nb2, 16);       // quads hold disjoint k-slices of same q
        nb2 += __shfl_xor(nb2, 32);
        const float rnb = 1.0f / sqrtf(nb2);
        bf[nt][0] = cvt8(v0, v1, rnb);
        bf[nt][1] = cvt8(v2, v3, rnb);
    }

    // ---- prologue: stage tile0 into buffer 0 ----
    {
        const f32x4* src = (const f32x4*)(acts + (size_t)tile0 * (TS * D));
        f32x4 v[4];
#pragma unroll
        for (int i = 0; i < 4; ++i) v[i] = src[tid + i * 256];   // dense 4 KB/inst
#pragma unroll
        for (int i = 0; i < 4; ++i) {
            const int c   = tid + i * 256;
            const int row = c >> 4, col = c & 15;
            float s = sq4(v[i]);
            s += __shfl_xor(s, 1); s += __shfl_xor(s, 2);
            s += __shfl_xor(s, 4); s += __shfl_xor(s, 8);
            *(short4v*)&As[0][row * ASTRIDE + col * 4] = cvt4(v[i], 1.0f / sqrtf(s));
        }
    }
    __syncthreads();

    int ti = 0;
    int p  = 0;
    while (true) {
        const bool have_next = (ti + 1) < cn;

        // ---- issue next tile's dense loads early (overlap MFMA) ----
        f32x4 v[4];
        if (have_next) {
            const f32x4* src =
                (const f32x4*)(acts + (size_t)(tile0 + ti + 1) * (TS * D));
#pragma unroll
            for (int i = 0; i < 4; ++i) v[i] = src[tid + i * 256];
        }

        // ---- MFMA on buffer p: A-frags shared across the wave's 2 nt-chunks ----
        short8 af[4][2];
#pragma unroll
        for (int mt = 0; mt < 4; ++mt)
#pragma unroll
            for (int ks = 0; ks < 2; ++ks)
                af[mt][ks] = *(const short8*)
                    &As[p][(mt * 16 + l15) * ASTRIDE + ks * 32 + quad * 8];

        f32x4 acc[2][4];
#pragma unroll
        for (int nt = 0; nt < 2; ++nt)
#pragma unroll
            for (int mt = 0; mt < 4; ++mt) acc[nt][mt] = (f32x4){0.f, 0.f, 0.f, 0.f};
#pragma unroll
        for (int ks = 0; ks < 2; ++ks)
#pragma unroll
            for (int nt = 0; nt < 2; ++nt)
#pragma unroll
                for (int mt = 0; mt < 4; ++mt)
                    acc[nt][mt] = __builtin_amdgcn_mfma_f32_16x16x32_bf16(
                        af[mt][ks], bf[nt][ks], acc[nt][mt], 0, 0, 0);

        // ---- epilogue: per-(q,tile) max into LDS buffer ----
#pragma unroll
        for (int nt = 0; nt < 2; ++nt) {
            float m = -3.0e38f;
#pragma unroll
            for (int mt = 0; mt < 4; ++mt)
                m = fmaxf(m, fmaxf(fmaxf(acc[nt][mt].x, acc[nt][mt].y),
                                   fmaxf(acc[nt][mt].z, acc[nt][mt].w)));
            m = fmaxf(m, __shfl_xor(m, 16));
            m = fmaxf(m, __shfl_xor(m, 32));
            if (quad == 0) {
                const int q = (wv * 2 + nt) * 16 + l15;
                tbuf[q * CHUNK + ti] = m;   // stride-21 across 16 lanes: conflict-free
            }
        }

        if (!have_next) break;

        // ---- normalize+cvt next tile into buffer p^1 ----
#pragma unroll
        for (int i = 0; i < 4; ++i) {
            const int c   = tid + i * 256;
            const int row = c >> 4, col = c & 15;
            float s = sq4(v[i]);
            s += __shfl_xor(s, 1); s += __shfl_xor(s, 2);
            s += __shfl_xor(s, 4); s += __shfl_xor(s, 8);
            *(short4v*)&As[p ^ 1][row * ASTRIDE + col * 4] = cvt4(v[i], 1.0f / sqrtf(s));
        }
        __syncthreads();
        p ^= 1;
        ++ti;
    }

    // ---- coalesced flush: 21-float contiguous runs per q, each line <=2 writers ----
    __syncthreads();
    for (int idx = tid; idx < NQ * CHUNK; idx += 256) {
        const int q = idx / CHUNK;           // compile-time const divisor -> magic mul
        const int t = idx - q * CHUNK;
        if (t < cn) tmax[(size_t)q * ntiles + tile0 + t] = tbuf[idx];
    }
}

// K2: one block per query. Coalesced scan of tmax row for approx max, flag
// tiles within MARGIN (provably contains exact argmax), exact fp32 rescore
// spread over all 4 waves with a single deferred reduce.
__global__ __launch_bounds__(256, 2)
void k2_rescore(const float* __restrict__ pred,
                const float* __restrict__ acts,
                const float* __restrict__ tmax,
                float* __restrict__ out,
                int ntiles)
{
    __shared__ float wmax[4];
    __shared__ int   cnt;
    __shared__ int   list[CAP];
    __shared__ unsigned long long wbest[4];

    const int q    = blockIdx.x;
    const int tid  = threadIdx.x;
    const int lane = tid & 63;
    const int wv   = tid >> 6;
    const float* row = tmax + (size_t)q * ntiles;

    if (tid == 0) cnt = 0;
    float m = -3.0e38f;
    for (int t = tid; t < ntiles; t += 256) m = fmaxf(m, row[t]);
#pragma unroll
    for (int off = 1; off < 64; off <<= 1) m = fmaxf(m, __shfl_xor(m, off));
    if (lane == 0) wmax[wv] = m;
    __syncthreads();
    m = fmaxf(fmaxf(wmax[0], wmax[1]), fmaxf(wmax[2], wmax[3]));
    const float thr = m - MARGIN;

    for (int t = tid; t < ntiles; t += 256) {
        if (row[t] >= thr) {
            int i = atomicAdd(&cnt, 1);
            if (i < CAP) list[i] = t;
        }
    }
    __syncthreads();
    const int n = min(cnt, CAP);

    // ---- exact fp32 rescore: wave wv handles flagged tiles wv, wv+4, ... ----
    const f32x4* P = (const f32x4*)(pred + q * D);
    unsigned long long best = 0ull;
    for (int i = wv; i < n; i += 4) {
        const int r = list[i] * TS + lane;     // 64 lanes = 64 rows of the tile
        const f32x4* A = (const f32x4*)(acts + (size_t)r * D);
        float dot = 0.f, na2 = 0.f;
#pragma unroll
        for (int c = 0; c < 16; ++c) {
            f32x4 a  = A[c];
            f32x4 pq = P[c];
            dot = fmaf(a.x, pq.x, dot); na2 = fmaf(a.x, a.x, na2);
            dot = fmaf(a.y, pq.y, dot); na2 = fmaf(a.y, a.y, na2);
            dot = fmaf(a.z, pq.z, dot); na2 = fmaf(a.z, a.z, na2);
            dot = fmaf(a.w, pq.w, dot); na2 = fmaf(a.w, a.w, na2);
        }
        float sim = dot * (1.0f / sqrtf(na2));
        unsigned long long key =
            ((unsigned long long)ordf(sim) << 32) | (unsigned)(~r);
        if (key > best) best = key;            // reduce deferred to after the loop
    }
#pragma unroll
    for (int off = 1; off < 64; off <<= 1) {
        unsigned long long o = __shfl_xor(best, off);
        if (o > best) best = o;
    }
    if (lane == 0) wbest[wv] = best;
    __syncthreads();
    if (tid == 0) {
        unsigned long long b = wbest[0];
#pragma unroll
        for (int w = 1; w < 4; ++w) if (wbest[w] > b) b = wbest[w];
        wbest[0] = b;
    }
    __syncthreads();
    if (tid < 64) {
        const unsigned idx = ~(unsigned)(wbest[0] & 0xffffffffull);
        out[q * D + tid] = acts[(size_t)idx * D + tid];
    }
}

extern "C" void kernel_launch(void* const* d_in, const int* in_sizes, int n_in,
                              void* d_out, int out_size, void* d_ws, size_t ws_size,
                              hipStream_t stream)
{
    const float* pred = (const float*)d_in[0];   // (32,4,64)
    const float* acts = (const float*)d_in[1];   // (1000000,64)
    long n0 = in_sizes[0], n1 = in_sizes[1];
    if (n0 > n1) {                                // defensive: acts is the big one
        const float* t = pred; pred = acts; acts = t;
        long tt = n0; n0 = n1; n1 = tt;
    }
    const int N      = (int)(n1 / D);
    const int ntiles = N / TS;                    // 1e6/64 = 15625
    const int nblk   = (ntiles + CHUNK - 1) / CHUNK;   // 745

    float* tmax = (float*)d_ws;                   // [q][tile]: 128*15625*4 = 8 MB
    float* out  = (float*)d_out;

    k1_score<<<dim3(nblk), dim3(256), 0, stream>>>(pred, acts, tmax, ntiles);
    k2_rescore<<<dim3(NQ), dim3(256), 0, stream>>>(pred, acts, tmax, out, ntiles);
}

// Round 2
// 367.899 us; speedup vs baseline: 1.0400x; 1.0400x over previous
//
#include <hip/hip_runtime.h>
#include <hip/hip_bf16.h>
#include <math.h>

#define D        64      // feature dim
#define NQ       128     // 32*4 queries
#define TS       64      // action rows per tile
#define ASTRIDE  72      // bf16 elems per LDS row: 144 B, 16B-aligned, <=2-way bank alias (free)
#define MARGIN   0.025f  // > 2*(bf16 RNE cosine error bound ~0.008)
#define CAP      128     // max flagged tiles per query
#define CCAP     64      // max flagged chunks per query
#define CHUNK    21      // contiguous tiles per block: 745 blocks, all resident at 3/CU

typedef __attribute__((ext_vector_type(8))) short  short8;
typedef __attribute__((ext_vector_type(4))) short  short4v;
typedef __attribute__((ext_vector_type(4))) float  f32x4;

__device__ inline unsigned ordf(float f) {
    unsigned u = __float_as_uint(f);
    return (u & 0x80000000u) ? ~u : (u | 0x80000000u);
}

__device__ inline short bf16bits(float f) {
    __hip_bfloat16 h = __float2bfloat16(f);
    return *(short*)&h;
}

__device__ inline float sq4(f32x4 a) {
    float s = 0.f;
    s = fmaf(a.x, a.x, s); s = fmaf(a.y, a.y, s);
    s = fmaf(a.z, a.z, s); s = fmaf(a.w, a.w, s);
    return s;
}

__device__ inline float sq16(f32x4 a, f32x4 b, f32x4 c, f32x4 d) {
    return sq4(a) + sq4(b) + sq4(c) + sq4(d);
}

__device__ inline short8 cvt8(f32x4 a, f32x4 b, float s) {
    short8 r;
    r[0] = bf16bits(a.x * s); r[1] = bf16bits(a.y * s);
    r[2] = bf16bits(a.z * s); r[3] = bf16bits(a.w * s);
    r[4] = bf16bits(b.x * s); r[5] = bf16bits(b.y * s);
    r[6] = bf16bits(b.z * s); r[7] = bf16bits(b.w * s);
    return r;
}

__device__ inline short4v cvt4(f32x4 a, float s) {
    short4v r;
    r[0] = bf16bits(a.x * s); r[1] = bf16bits(a.y * s);
    r[2] = bf16bits(a.z * s); r[3] = bf16bits(a.w * s);
    return r;
}

// K1: block-per-CHUNK of contiguous tiles, double-buffered bf16 LDS tile.
// Per-(q,tile) maxes accumulate in LDS (tbuf); at block end flush (a) the fine
// per-tile maxes (coalesced 21-float runs) and (b) a per-(q,chunk) max so K2's
// scan domain shrinks 21x (15625 -> 745 floats per query).
__global__ __launch_bounds__(256, 3)
void k1_score(const float* __restrict__ pred,
              const float* __restrict__ acts,
              float* __restrict__ tmax,
              float* __restrict__ tmax2,
              int ntiles, int nchunk)
{
    __shared__ unsigned short As[2][TS * ASTRIDE];   // normalized bf16 tiles
    __shared__ float tbuf[NQ * CHUNK];               // per-(q,tile) maxes, 10.5 KB

    const int tid  = threadIdx.x;
    const int lane = tid & 63;
    const int wv   = tid >> 6;      // 0..3
    const int quad = lane >> 4;     // 0..3
    const int l15  = lane & 15;

    const int tile0 = blockIdx.x * CHUNK;
    if (tile0 >= ntiles) return;
    const int cn = min(CHUNK, ntiles - tile0);

    // ---- B frags: wave's 32 queries, normalized, bf16. q=(wv*2+nt)*16+l15 ----
    short8 bf[2][2];
#pragma unroll
    for (int nt = 0; nt < 2; ++nt) {
        const int q = (wv * 2 + nt) * 16 + l15;
        const float* P = pred + q * D + quad * 8;
        f32x4 v0 = *(const f32x4*)(P);
        f32x4 v1 = *(const f32x4*)(P + 4);
        f32x4 v2 = *(const f32x4*)(P + 32);
        f32x4 v3 = *(const f32x4*)(P + 36);
        float nb2 = sq16(v0, v1, v2, v3);
        nb2 += __shfl_xor(nb2, 16);       // quads hold disjoint k-slices of same q
        nb2 += __shfl_xor(nb2, 32);
        const float rnb = 1.0f / sqrtf(nb2);
        bf[nt][0] = cvt8(v0, v1, rnb);
        bf[nt][1] = cvt8(v2, v3, rnb);
    }

    // ---- prologue: stage tile0 into buffer 0 ----
    {
        const f32x4* src = (const f32x4*)(acts + (size_t)tile0 * (TS * D));
        f32x4 v[4];
#pragma unroll
        for (int i = 0; i < 4; ++i) v[i] = src[tid + i * 256];   // dense 4 KB/inst
#pragma unroll
        for (int i = 0; i < 4; ++i) {
            const int c   = tid + i * 256;
            const int row = c >> 4, col = c & 15;
            float s = sq4(v[i]);
            s += __shfl_xor(s, 1); s += __shfl_xor(s, 2);
            s += __shfl_xor(s, 4); s += __shfl_xor(s, 8);
            *(short4v*)&As[0][row * ASTRIDE + col * 4] = cvt4(v[i], 1.0f / sqrtf(s));
        }
    }
    __syncthreads();

    int ti = 0;
    int p  = 0;
    while (true) {
        const bool have_next = (ti + 1) < cn;

        // ---- issue next tile's dense loads early (overlap MFMA) ----
        f32x4 v[4];
        if (have_next) {
            const f32x4* src =
                (const f32x4*)(acts + (size_t)(tile0 + ti + 1) * (TS * D));
#pragma unroll
            for (int i = 0; i < 4; ++i) v[i] = src[tid + i * 256];
        }

        // ---- MFMA on buffer p: A-frags shared across the wave's 2 nt-chunks ----
        short8 af[4][2];
#pragma unroll
        for (int mt = 0; mt < 4; ++mt)
#pragma unroll
            for (int ks = 0; ks < 2; ++ks)
                af[mt][ks] = *(const short8*)
                    &As[p][(mt * 16 + l15) * ASTRIDE + ks * 32 + quad * 8];

        f32x4 acc[2][4];
#pragma unroll
        for (int nt = 0; nt < 2; ++nt)
#pragma unroll
            for (int mt = 0; mt < 4; ++mt) acc[nt][mt] = (f32x4){0.f, 0.f, 0.f, 0.f};
#pragma unroll
        for (int ks = 0; ks < 2; ++ks)
#pragma unroll
            for (int nt = 0; nt < 2; ++nt)
#pragma unroll
                for (int mt = 0; mt < 4; ++mt)
                    acc[nt][mt] = __builtin_amdgcn_mfma_f32_16x16x32_bf16(
                        af[mt][ks], bf[nt][ks], acc[nt][mt], 0, 0, 0);

        // ---- epilogue: per-(q,tile) max into LDS buffer ----
#pragma unroll
        for (int nt = 0; nt < 2; ++nt) {
            float m = -3.0e38f;
#pragma unroll
            for (int mt = 0; mt < 4; ++mt)
                m = fmaxf(m, fmaxf(fmaxf(acc[nt][mt].x, acc[nt][mt].y),
                                   fmaxf(acc[nt][mt].z, acc[nt][mt].w)));
            m = fmaxf(m, __shfl_xor(m, 16));
            m = fmaxf(m, __shfl_xor(m, 32));
            if (quad == 0) {
                const int q = (wv * 2 + nt) * 16 + l15;
                tbuf[q * CHUNK + ti] = m;   // stride-21 across 16 lanes: conflict-free
            }
        }

        if (!have_next) break;

        // ---- normalize+cvt next tile into buffer p^1 ----
#pragma unroll
        for (int i = 0; i < 4; ++i) {
            const int c   = tid + i * 256;
            const int row = c >> 4, col = c & 15;
            float s = sq4(v[i]);
            s += __shfl_xor(s, 1); s += __shfl_xor(s, 2);
            s += __shfl_xor(s, 4); s += __shfl_xor(s, 8);
            *(short4v*)&As[p ^ 1][row * ASTRIDE + col * 4] = cvt4(v[i], 1.0f / sqrtf(s));
        }
        __syncthreads();
        p ^= 1;
        ++ti;
    }

    // ---- flush: fine per-tile maxes (coalesced 21-float runs per q) ----
    __syncthreads();
    for (int idx = tid; idx < NQ * CHUNK; idx += 256) {
        const int q = idx / CHUNK;           // compile-time const divisor -> magic mul
        const int t = idx - q * CHUNK;
        if (t < cn) tmax[(size_t)q * ntiles + tile0 + t] = tbuf[idx];
    }
    // ---- flush: per-(q,chunk) max. tbuf reads stride-21 across lanes: 21 odd
    // -> <=2-way bank alias (free). 381 KB total, L3-absorbed.
    if (tid < NQ) {
        float mm = -3.0e38f;
        for (int t = 0; t < cn; ++t) mm = fmaxf(mm, tbuf[tid * CHUNK + t]);
        tmax2[(size_t)tid * nchunk + blockIdx.x] = mm;
    }
}

// K2: one block per query. Max over the 745-float chunk-max row (3 strided
// iterations), flag chunks within MARGIN, expand only those chunks' fine tile
// maxes (identical flagged-tile set: chunkmax >= row[t] >= thr), exact fp32
// rescore over all 4 waves with one deferred reduce.
__global__ __launch_bounds__(256, 2)
void k2_rescore(const float* __restrict__ pred,
                const float* __restrict__ acts,
                const float* __restrict__ tmax,
                const float* __restrict__ tmax2,
                float* __restrict__ out,
                int ntiles, int nchunk)
{
    __shared__ float wmax[4];
    __shared__ int   ccnt, cnt;
    __shared__ int   clist[CCAP];
    __shared__ int   list[CAP];
    __shared__ unsigned long long wbest[4];

    const int q    = blockIdx.x;
    const int tid  = threadIdx.x;
    const int lane = tid & 63;
    const int wv   = tid >> 6;
    const float* row  = tmax  + (size_t)q * ntiles;
    const float* row2 = tmax2 + (size_t)q * nchunk;

    if (tid == 0) { ccnt = 0; cnt = 0; }

    // ---- global bf16 max from the coarse row (745 floats) ----
    float m = -3.0e38f;
    for (int c = tid; c < nchunk; c += 256) m = fmaxf(m, row2[c]);
#pragma unroll
    for (int off = 1; off < 64; off <<= 1) m = fmaxf(m, __shfl_xor(m, off));
    if (lane == 0) wmax[wv] = m;
    __syncthreads();
    m = fmaxf(fmaxf(wmax[0], wmax[1]), fmaxf(wmax[2], wmax[3]));
    const float thr = m - MARGIN;

    // ---- flag chunks within margin ----
    for (int c = tid; c < nchunk; c += 256) {
        if (row2[c] >= thr) {
            int i = atomicAdd(&ccnt, 1);
            if (i < CCAP) clist[i] = c;
        }
    }
    __syncthreads();
    const int nc = min(ccnt, CCAP);

    // ---- expand flagged chunks to flagged tiles (reads ~nc*21 floats) ----
    for (int j = tid; j < nc * CHUNK; j += 256) {
        const int ci = j / CHUNK;            // const divisor -> magic mul
        const int t  = j - ci * CHUNK;
        const int tile = clist[ci] * CHUNK + t;
        if (tile < ntiles && row[tile] >= thr) {
            int i = atomicAdd(&cnt, 1);
            if (i < CAP) list[i] = tile;
        }
    }
    __syncthreads();
    const int n = min(cnt, CAP);

    // ---- exact fp32 rescore: wave wv handles flagged tiles wv, wv+4, ... ----
    const f32x4* P = (const f32x4*)(pred + q * D);
    unsigned long long best = 0ull;
    for (int i = wv; i < n; i += 4) {
        const int r = list[i] * TS + lane;     // 64 lanes = 64 rows of the tile
        const f32x4* A = (const f32x4*)(acts + (size_t)r * D);
        float dot = 0.f, na2 = 0.f;
#pragma unroll
        for (int c = 0; c < 16; ++c) {
            f32x4 a  = A[c];
            f32x4 pq = P[c];
            dot = fmaf(a.x, pq.x, dot); na2 = fmaf(a.x, a.x, na2);
            dot = fmaf(a.y, pq.y, dot); na2 = fmaf(a.y, a.y, na2);
            dot = fmaf(a.z, pq.z, dot); na2 = fmaf(a.z, a.z, na2);
            dot = fmaf(a.w, pq.w, dot); na2 = fmaf(a.w, a.w, na2);
        }
        float sim = dot * (1.0f / sqrtf(na2));
        unsigned long long key =
            ((unsigned long long)ordf(sim) << 32) | (unsigned)(~r);
        if (key > best) best = key;            // reduce deferred to after the loop
    }
#pragma unroll
    for (int off = 1; off < 64; off <<= 1) {
        unsigned long long o = __shfl_xor(best, off);
        if (o > best) best = o;
    }
    if (lane == 0) wbest[wv] = best;
    __syncthreads();
    if (tid == 0) {
        unsigned long long b = wbest[0];
#pragma unroll
        for (int w = 1; w < 4; ++w) if (wbest[w] > b) b = wbest[w];
        wbest[0] = b;
    }
    __syncthreads();
    if (tid < 64) {
        const unsigned idx = ~(unsigned)(wbest[0] & 0xffffffffull);
        out[q * D + tid] = acts[(size_t)idx * D + tid];
    }
}

extern "C" void kernel_launch(void* const* d_in, const int* in_sizes, int n_in,
                              void* d_out, int out_size, void* d_ws, size_t ws_size,
                              hipStream_t stream)
{
    const float* pred = (const float*)d_in[0];   // (32,4,64)
    const float* acts = (const float*)d_in[1];   // (1000000,64)
    long n0 = in_sizes[0], n1 = in_sizes[1];
    if (n0 > n1) {                                // defensive: acts is the big one
        const float* t = pred; pred = acts; acts = t;
        long tt = n0; n0 = n1; n1 = tt;
    }
    const int N      = (int)(n1 / D);
    const int ntiles = N / TS;                    // 1e6/64 = 15625
    const int nchunk = (ntiles + CHUNK - 1) / CHUNK;   // 745

    float* tmax  = (float*)d_ws;                  // [q][tile]:  128*15625*4 = 8 MB
    float* tmax2 = tmax + (size_t)NQ * ntiles;    // [q][chunk]: 128*745*4 = 381 KB
    float* out   = (float*)d_out;

    k1_score<<<dim3(nchunk), dim3(256), 0, stream>>>(pred, acts, tmax, tmax2,
                                                     ntiles, nchunk);
    k2_rescore<<<dim3(NQ), dim3(256), 0, stream>>>(pred, acts, tmax, tmax2, out,
                                                   ntiles, nchunk);
}